// Round 2
// baseline (1255.620 us; speedup 1.0000x reference)
//
#include <hip/hip_runtime.h>
#include <stdint.h>

#define NG   32
#define NPG  512
#define EPG  4096
#define DN   128
#define DP   64
#define NN   (NG*NPG)          // 16384 nodes
#define NE   (NG*EPG)          // 131072 edges
#define KD   320               // in_dim
#define HD   768               // hidden
#define SEQ  (1+NPG+EPG)       // 4609
#define TOK_ELEMS ((size_t)NG*SEQ*HD)
#define MASK_ELEMS ((size_t)NG*SEQ)

#define APAD 328   // 320+8 shorts: 656B row stride, 16B aligned
#define BPAD 40    // 32+8 shorts:  80B row stride

typedef unsigned short u16;
typedef __attribute__((ext_vector_type(8))) __bf16 bf16x8;
typedef __attribute__((ext_vector_type(8))) short  s16x8;
typedef __attribute__((ext_vector_type(4))) float  f32x4;

__device__ __forceinline__ u16 f2bf(float f) {
    uint32_t u = __builtin_bit_cast(uint32_t, f);
    u += 0x7fffu + ((u >> 16) & 1u);          // RNE
    return (u16)(u >> 16);
}

// ---------------- aux kernels ----------------
__global__ void zero_k(int* p) { if (threadIdx.x < 64) p[threadIdx.x] = 0; }

__global__ void count_k(const int* __restrict__ batch, const int* __restrict__ eidx,
                        int* __restrict__ ncnt, int* __restrict__ ecnt) {
    int i = blockIdx.x * 256 + threadIdx.x;
    if (i < NN) atomicAdd(&ncnt[batch[i]], 1);
    if (i < NE) atomicAdd(&ecnt[batch[eidx[i]]], 1);
}

__global__ void scan_k(const int* __restrict__ ncnt, const int* __restrict__ ecnt,
                       int* __restrict__ nptr, int* __restrict__ eptr) {
    int g = threadIdx.x;
    if (g < NG) {
        int sn = 0, se = 0;
        for (int j = 0; j < g; ++j) { sn += ncnt[j]; se += ecnt[j]; }
        nptr[g] = sn; eptr[g] = se;
    }
}

__global__ void wconv_k(const float* __restrict__ W, u16* __restrict__ Wb) {
    int i = blockIdx.x * 256 + threadIdx.x;
    if (i < KD * HD) Wb[i] = f2bf(W[i]);       // keep [H][K] row-major layout
}

__global__ void aux_k(const float* __restrict__ gt, float* __restrict__ out) {
    size_t i = (size_t)blockIdx.x * 256 + threadIdx.x;
    if (i < (size_t)NG * HD) {
        int g = (int)(i / HD), c = (int)(i % HD);
        out[(size_t)g * SEQ * HD + c] = gt[c];           // [graph] token row
    } else {
        size_t m = i - (size_t)NG * HD;
        if (m < MASK_ELEMS) out[TOK_ELEMS + m] = 1.0f;   // mask = True -> 1.0f
    }
}

// ---------------- main fused gather-GEMM-scatter ----------------
// block = 256 threads (4 waves), 64 A-rows per block; wave w owns rows
// [w*16, w*16+16), all 128 cols of the current col-tile.
__global__ __launch_bounds__(256)
void gemm_scatter(const float* __restrict__ x,  const float* __restrict__ ea,
                  const float* __restrict__ P,  const float* __restrict__ EV,
                  const float* __restrict__ EEv,const float* __restrict__ bias,
                  const int* __restrict__ eidx, const int* __restrict__ batch,
                  const u16* __restrict__ Wb,   const int* __restrict__ nptr,
                  const int* __restrict__ eptr, float* __restrict__ out)
{
    __shared__ __align__(16) u16 a_full[64 * APAD];   // 41984 B
    __shared__ __align__(16) u16 b_tile[128 * BPAD];  // 10240 B
    __shared__ int info_src[64], info_pu[64], info_pv[64], info_orow[64];

    const int tid = threadIdx.x;
    const int r0  = blockIdx.x * 64;
    const bool isNode = (r0 < NN);
    const float* feat = isNode ? x  : ea;
    const float* idv  = isNode ? EV : EEv;

    if (tid < 64) {
        int r = r0 + tid;
        if (isNode) {
            int g = batch[r];
            info_src[tid] = r; info_pu[tid] = r; info_pv[tid] = r;
            info_orow[tid] = g * SEQ + 1 + (r - nptr[g]);
        } else {
            int e = r - NN;
            int s = eidx[e], d = eidx[NE + e];
            int g = batch[s];
            info_src[tid] = e; info_pu[tid] = s; info_pv[tid] = d;
            info_orow[tid] = g * SEQ + 1 + NPG + (e - eptr[g]);
        }
    }
    __syncthreads();

    // ---- stage full 64x320 A panel (fp32 -> bf16) ----
    {
        const int arow = tid >> 2;
        const int ac   = (tid & 3) * 8;
        const int fsrc = info_src[arow];
        const int pu   = info_pu[arow];
        const int pv   = info_pv[arow];
        #pragma unroll
        for (int s = 0; s < KD / 32; ++s) {
            const int kg = s * 32 + ac;
            const float* sp;
            if      (s < 4) sp = feat + (size_t)fsrc * DN + kg;
            else if (s < 6) sp = P + (size_t)pu * DP + (kg - DN);
            else if (s < 8) sp = P + (size_t)pv * DP + (kg - DN - DP);
            else            sp = idv + (kg - DN - 2 * DP);
            f32x4 f0 = *reinterpret_cast<const f32x4*>(sp);
            f32x4 f1 = *reinterpret_cast<const f32x4*>(sp + 4);
            s16x8 v;
            v[0]=(short)f2bf(f0[0]); v[1]=(short)f2bf(f0[1]);
            v[2]=(short)f2bf(f0[2]); v[3]=(short)f2bf(f0[3]);
            v[4]=(short)f2bf(f1[0]); v[5]=(short)f2bf(f1[1]);
            v[6]=(short)f2bf(f1[2]); v[7]=(short)f2bf(f1[3]);
            *reinterpret_cast<s16x8*>(&a_full[arow * APAD + kg]) = v;
        }
    }
    // (first b-tile barrier below also fences the A-panel stores)

    const int lane = tid & 63;
    const int wid  = tid >> 6;
    const int lrow = lane & 15;
    const int lq   = lane >> 4;

    // per-lane output rows (constant across col tiles)
    size_t my_row_base[4];
    #pragma unroll
    for (int j = 0; j < 4; ++j)
        my_row_base[j] = (size_t)info_orow[wid * 16 + lq * 4 + j] * HD;

    for (int nt = 0; nt < HD / 128; ++nt) {
        const int n0 = nt * 128;
        f32x4 acc[8];
        #pragma unroll
        for (int i = 0; i < 8; ++i) acc[i] = (f32x4)0.f;

        for (int kt = 0; kt < KD / 32; ++kt) {
            #pragma unroll
            for (int t = 0; t < 2; ++t) {               // stage B: 128 W-rows x 32 k
                int u  = tid + t * 256;
                int nl = u >> 2;
                int c  = (u & 3) * 8;
                *reinterpret_cast<s16x8*>(&b_tile[nl * BPAD + c]) =
                    *reinterpret_cast<const s16x8*>(&Wb[(size_t)(n0 + nl) * KD + kt * 32 + c]);
            }
            __syncthreads();
            bf16x8 af = *reinterpret_cast<const bf16x8*>(
                &a_full[(wid * 16 + lrow) * APAD + kt * 32 + lq * 8]);
            #pragma unroll
            for (int ni = 0; ni < 8; ++ni) {
                bf16x8 bf = *reinterpret_cast<const bf16x8*>(
                    &b_tile[(ni * 16 + lrow) * BPAD + lq * 8]);
                acc[ni] = __builtin_amdgcn_mfma_f32_16x16x32_bf16(af, bf, acc[ni], 0, 0, 0);
            }
            __syncthreads();
        }

        // ---- epilogue: bias + direct f32 scatter stores ----
        #pragma unroll
        for (int ni = 0; ni < 8; ++ni) {
            float bv = bias[n0 + ni * 16 + lrow];
            #pragma unroll
            for (int j = 0; j < 4; ++j)
                out[my_row_base[j] + n0 + ni * 16 + lrow] = acc[ni][j] + bv;
        }
    }
}

extern "C" void kernel_launch(void* const* d_in, const int* in_sizes, int n_in,
                              void* d_out, int out_size, void* d_ws, size_t ws_size,
                              hipStream_t stream) {
    const float* x    = (const float*)d_in[0];
    const float* ea   = (const float*)d_in[1];
    const float* P    = (const float*)d_in[2];
    const float* EV   = (const float*)d_in[3];
    const float* EEv  = (const float*)d_in[4];
    const float* W    = (const float*)d_in[5];
    const float* bias = (const float*)d_in[6];
    const float* gt   = (const float*)d_in[7];
    const int* eidx   = (const int*)d_in[8];
    const int* batch  = (const int*)d_in[9];

    float* out = (float*)d_out;
    u16* Wb  = (u16*)d_ws;
    int* ints = (int*)((char*)d_ws + (size_t)KD * HD * 2);
    int *ncnt = ints, *ecnt = ints + 32, *nptr = ints + 64, *eptr = ints + 96;

    zero_k<<<1, 64, 0, stream>>>(ints);
    count_k<<<(NE + 255) / 256, 256, 0, stream>>>(batch, eidx, ncnt, ecnt);
    scan_k<<<1, 64, 0, stream>>>(ncnt, ecnt, nptr, eptr);
    wconv_k<<<(KD * HD + 255) / 256, 256, 0, stream>>>(W, Wb);
    aux_k<<<(int)(((size_t)NG * HD + MASK_ELEMS + 255) / 256), 256, 0, stream>>>(gt, out);
    gemm_scatter<<<dim3((NN + NE) / 64), 256, 0, stream>>>(
        x, ea, P, EV, EEv, bias, eidx, batch, Wb, nptr, eptr, out);
}

// Round 3
// 201.039 us; speedup vs baseline: 6.2456x; 6.2456x over previous
//
#include <hip/hip_runtime.h>
#include <stdint.h>

#define NG   32
#define NPG  512
#define EPG  4096
#define DN   128
#define DP   64
#define NN   (NG*NPG)          // 16384 nodes
#define NE   (NG*EPG)          // 131072 edges
#define KD   320               // in_dim
#define HD   768               // hidden
#define SEQ  (1+NPG+EPG)       // 4609
#define TOK_ELEMS ((size_t)NG*SEQ*HD)
#define MASK_ELEMS ((size_t)NG*SEQ)

#define APAD 328   // 320+8 shorts: 656B row stride, 16B aligned
#define BPAD 40    // 32+8 shorts:  80B row stride -> 2-way bank alias (free, m136)

typedef unsigned short u16;
typedef __attribute__((ext_vector_type(8))) __bf16 bf16x8;
typedef __attribute__((ext_vector_type(8))) short  s16x8;
typedef __attribute__((ext_vector_type(4))) float  f32x4;

__device__ __forceinline__ u16 f2bf(float f) {
    uint32_t u = __builtin_bit_cast(uint32_t, f);
    u += 0x7fffu + ((u >> 16) & 1u);          // RNE
    return (u16)(u >> 16);
}

// ---------------- aux kernels ----------------
// Exclusive prefix pointers via binary search (batch / edge-graph-id are
// sorted non-decreasing — required by the reference's packing semantics).
// Replaces the atomic histogram that cost 1090 us (64-address contention).
__global__ void ptr_k(const int* __restrict__ batch, const int* __restrict__ eidx,
                      int* __restrict__ nptr, int* __restrict__ eptr) {
    int t = threadIdx.x;
    if (t < NG) {
        int g = t, lo = 0, hi = NN;
        while (lo < hi) { int mid = (lo + hi) >> 1; if (batch[mid] < g) lo = mid + 1; else hi = mid; }
        nptr[g] = lo;
    } else if (t < 2 * NG) {
        int g = t - NG, lo = 0, hi = NE;
        while (lo < hi) { int mid = (lo + hi) >> 1; if (batch[eidx[mid]] < g) lo = mid + 1; else hi = mid; }
        eptr[g] = lo;
    }
}

__global__ void wconv_k(const float* __restrict__ W, u16* __restrict__ Wb) {
    int i = blockIdx.x * 256 + threadIdx.x;
    if (i < KD * HD) Wb[i] = f2bf(W[i]);       // keep [H][K] row-major layout
}

__global__ void aux_k(const float* __restrict__ gt, float* __restrict__ out) {
    size_t i = (size_t)blockIdx.x * 256 + threadIdx.x;
    if (i < (size_t)NG * HD) {
        int g = (int)(i / HD), c = (int)(i % HD);
        out[(size_t)g * SEQ * HD + c] = gt[c];           // [graph] token row
    } else {
        size_t m = i - (size_t)NG * HD;
        if (m < MASK_ELEMS) out[TOK_ELEMS + m] = 1.0f;   // mask = True -> 1.0f
    }
}

// ---------------- main fused gather-GEMM-scatter ----------------
// block = 256 threads (4 waves), 64 A-rows per block; wave w owns rows
// [w*16, w*16+16), all 128 cols of the current col-tile.
__global__ __launch_bounds__(256)
void gemm_scatter(const float* __restrict__ x,  const float* __restrict__ ea,
                  const float* __restrict__ P,  const float* __restrict__ EV,
                  const float* __restrict__ EEv,const float* __restrict__ bias,
                  const int* __restrict__ eidx, const int* __restrict__ batch,
                  const u16* __restrict__ Wb,   const int* __restrict__ nptr,
                  const int* __restrict__ eptr, float* __restrict__ out)
{
    __shared__ __align__(16) u16 a_full[64 * APAD];   // 41984 B
    __shared__ __align__(16) u16 b_tile[128 * BPAD];  // 10240 B
    __shared__ int info_src[64], info_pu[64], info_pv[64], info_orow[64];

    const int tid = threadIdx.x;
    const int r0  = blockIdx.x * 64;
    const bool isNode = (r0 < NN);
    const float* feat = isNode ? x  : ea;
    const float* idv  = isNode ? EV : EEv;

    if (tid < 64) {
        int r = r0 + tid;
        if (isNode) {
            int g = batch[r];
            info_src[tid] = r; info_pu[tid] = r; info_pv[tid] = r;
            info_orow[tid] = g * SEQ + 1 + (r - nptr[g]);
        } else {
            int e = r - NN;
            int s = eidx[e], d = eidx[NE + e];
            int g = batch[s];
            info_src[tid] = e; info_pu[tid] = s; info_pv[tid] = d;
            info_orow[tid] = g * SEQ + 1 + NPG + (e - eptr[g]);
        }
    }
    __syncthreads();

    // ---- stage full 64x320 A panel (fp32 -> bf16) ----
    {
        const int arow = tid >> 2;
        const int ac   = (tid & 3) * 8;
        const int fsrc = info_src[arow];
        const int pu   = info_pu[arow];
        const int pv   = info_pv[arow];
        #pragma unroll
        for (int s = 0; s < KD / 32; ++s) {
            const int kg = s * 32 + ac;
            const float* sp;
            if      (s < 4) sp = feat + (size_t)fsrc * DN + kg;
            else if (s < 6) sp = P + (size_t)pu * DP + (kg - DN);
            else if (s < 8) sp = P + (size_t)pv * DP + (kg - DN - DP);
            else            sp = idv + (kg - DN - 2 * DP);
            f32x4 f0 = *reinterpret_cast<const f32x4*>(sp);
            f32x4 f1 = *reinterpret_cast<const f32x4*>(sp + 4);
            s16x8 v;
            v[0]=(short)f2bf(f0[0]); v[1]=(short)f2bf(f0[1]);
            v[2]=(short)f2bf(f0[2]); v[3]=(short)f2bf(f0[3]);
            v[4]=(short)f2bf(f1[0]); v[5]=(short)f2bf(f1[1]);
            v[6]=(short)f2bf(f1[2]); v[7]=(short)f2bf(f1[3]);
            *reinterpret_cast<s16x8*>(&a_full[arow * APAD + kg]) = v;
        }
    }
    // (first b-tile barrier below also fences the A-panel stores)

    const int lane = tid & 63;
    const int wid  = tid >> 6;
    const int lrow = lane & 15;
    const int lq   = lane >> 4;

    // per-lane output rows (constant across col tiles)
    size_t my_row_base[4];
    #pragma unroll
    for (int j = 0; j < 4; ++j)
        my_row_base[j] = (size_t)info_orow[wid * 16 + lq * 4 + j] * HD;

    for (int nt = 0; nt < HD / 128; ++nt) {
        const int n0 = nt * 128;
        f32x4 acc[8];
        #pragma unroll
        for (int i = 0; i < 8; ++i) acc[i] = (f32x4)0.f;

        for (int kt = 0; kt < KD / 32; ++kt) {
            #pragma unroll
            for (int t = 0; t < 2; ++t) {               // stage B: 128 W-rows x 32 k
                int u  = tid + t * 256;
                int nl = u >> 2;
                int c  = (u & 3) * 8;
                *reinterpret_cast<s16x8*>(&b_tile[nl * BPAD + c]) =
                    *reinterpret_cast<const s16x8*>(&Wb[(size_t)(n0 + nl) * KD + kt * 32 + c]);
            }
            __syncthreads();
            bf16x8 af = *reinterpret_cast<const bf16x8*>(
                &a_full[(wid * 16 + lrow) * APAD + kt * 32 + lq * 8]);
            #pragma unroll
            for (int ni = 0; ni < 8; ++ni) {
                bf16x8 bf = *reinterpret_cast<const bf16x8*>(
                    &b_tile[(ni * 16 + lrow) * BPAD + lq * 8]);
                acc[ni] = __builtin_amdgcn_mfma_f32_16x16x32_bf16(af, bf, acc[ni], 0, 0, 0);
            }
            __syncthreads();
        }

        // ---- epilogue: bias + direct f32 scatter stores ----
        #pragma unroll
        for (int ni = 0; ni < 8; ++ni) {
            float bv = bias[n0 + ni * 16 + lrow];
            #pragma unroll
            for (int j = 0; j < 4; ++j)
                out[my_row_base[j] + n0 + ni * 16 + lrow] = acc[ni][j] + bv;
        }
    }
}

extern "C" void kernel_launch(void* const* d_in, const int* in_sizes, int n_in,
                              void* d_out, int out_size, void* d_ws, size_t ws_size,
                              hipStream_t stream) {
    const float* x    = (const float*)d_in[0];
    const float* ea   = (const float*)d_in[1];
    const float* P    = (const float*)d_in[2];
    const float* EV   = (const float*)d_in[3];
    const float* EEv  = (const float*)d_in[4];
    const float* W    = (const float*)d_in[5];
    const float* bias = (const float*)d_in[6];
    const float* gt   = (const float*)d_in[7];
    const int* eidx   = (const int*)d_in[8];
    const int* batch  = (const int*)d_in[9];

    float* out = (float*)d_out;
    u16* Wb  = (u16*)d_ws;
    int* ints = (int*)((char*)d_ws + (size_t)KD * HD * 2);
    int *nptr = ints, *eptr = ints + 32;

    ptr_k<<<1, 64, 0, stream>>>(batch, eidx, nptr, eptr);
    wconv_k<<<(KD * HD + 255) / 256, 256, 0, stream>>>(W, Wb);
    aux_k<<<(int)(((size_t)NG * HD + MASK_ELEMS + 255) / 256), 256, 0, stream>>>(gt, out);
    gemm_scatter<<<dim3((NN + NE) / 64), 256, 0, stream>>>(
        x, ea, P, EV, EEv, bias, eidx, batch, Wb, nptr, eptr, out);
}

// Round 4
// 178.244 us; speedup vs baseline: 7.0444x; 1.1279x over previous
//
#include <hip/hip_runtime.h>
#include <stdint.h>

#define NG   32
#define NPG  512
#define EPG  4096
#define DN   128
#define DP   64
#define NN   (NG*NPG)          // 16384 nodes
#define NE   (NG*EPG)          // 131072 edges
#define KD   320               // in_dim
#define HD   768               // hidden
#define SEQ  (1+NPG+EPG)       // 4609
#define TOK_ELEMS ((size_t)NG*SEQ*HD)
#define MASK_ELEMS ((size_t)NG*SEQ)

typedef unsigned short u16;
typedef __attribute__((ext_vector_type(8))) __bf16 bf16x8;
typedef __attribute__((ext_vector_type(8))) short  s16x8;
typedef __attribute__((ext_vector_type(4))) float  f32x4;

__device__ __forceinline__ u16 f2bf(float f) {
    uint32_t u = __builtin_bit_cast(uint32_t, f);
    u += 0x7fffu + ((u >> 16) & 1u);          // RNE
    return (u16)(u >> 16);
}

// B-tile LDS layout: 128 W-rows x 32 k (bf16), rows pair-packed into 128B
// lines, 16B k-slots XOR-swizzled by bits of the row pair index so that a
// 16-row column-slice ds_read_b128 is 2-way (free) instead of 4-8-way.
// Same formula on write and read side (both-sides-or-neither rule).
__device__ __forceinline__ int b_off(int row, int kb) {
    return ((row >> 1) << 7) + ((row & 1) << 6) + (kb ^ (((row >> 1) & 3) << 4));
}

// ---------------- aux kernels ----------------
// Exclusive prefix pointers via binary search (batch / edge graph ids are
// sorted non-decreasing per the reference's packing semantics).
__global__ void ptr_k(const int* __restrict__ batch, const int* __restrict__ eidx,
                      int* __restrict__ nptr, int* __restrict__ eptr) {
    int t = threadIdx.x;
    if (t < NG) {
        int g = t, lo = 0, hi = NN;
        while (lo < hi) { int mid = (lo + hi) >> 1; if (batch[mid] < g) lo = mid + 1; else hi = mid; }
        nptr[g] = lo;
    } else if (t < 2 * NG) {
        int g = t - NG, lo = 0, hi = NE;
        while (lo < hi) { int mid = (lo + hi) >> 1; if (batch[eidx[mid]] < g) lo = mid + 1; else hi = mid; }
        eptr[g] = lo;
    }
}

__global__ void wconv_k(const float* __restrict__ W, u16* __restrict__ Wb) {
    int i = blockIdx.x * 256 + threadIdx.x;
    if (i < KD * HD) Wb[i] = f2bf(W[i]);       // keep [H][K] row-major layout
}

__global__ void aux_k(const float* __restrict__ gt, float* __restrict__ out) {
    size_t i = (size_t)blockIdx.x * 256 + threadIdx.x;
    if (i < (size_t)NG * HD) {
        int g = (int)(i / HD), c = (int)(i % HD);
        out[(size_t)g * SEQ * HD + c] = gt[c];           // [graph] token row
    } else {
        size_t m = i - (size_t)NG * HD;
        if (m < MASK_ELEMS) out[TOK_ELEMS + m] = 1.0f;   // mask = True -> 1.0f
    }
}

// ---------------- main fused gather-GEMM-scatter ----------------
// block = 256 threads (4 waves), 64 A-rows per block; wave w owns rows
// [w*16, w*16+16). A fragments live in registers (10 x bf16x8 per lane).
// B tiles (128 W-rows x 32 k) are double-buffered in LDS with a 1-K-step
// register prefetch: one raw s_barrier per K-step, no vmcnt(0) drain.
__global__ __launch_bounds__(256)
void gemm_scatter(const float* __restrict__ x,  const float* __restrict__ ea,
                  const float* __restrict__ P,  const float* __restrict__ EV,
                  const float* __restrict__ EEv,const float* __restrict__ bias,
                  const int* __restrict__ eidx, const int* __restrict__ batch,
                  const u16* __restrict__ Wb,   const int* __restrict__ nptr,
                  const int* __restrict__ eptr, float* __restrict__ out)
{
    __shared__ __align__(16) char b_lds[2][8192];
    __shared__ int info_src[64], info_pu[64], info_pv[64], info_orow[64];

    const int tid = threadIdx.x;
    const int r0  = blockIdx.x * 64;
    const bool isNode = (r0 < NN);
    const float* feat = isNode ? x  : ea;
    const float* idv  = isNode ? EV : EEv;

    if (tid < 64) {
        int r = r0 + tid;
        if (isNode) {
            int g = batch[r];
            info_src[tid] = r; info_pu[tid] = r; info_pv[tid] = r;
            info_orow[tid] = g * SEQ + 1 + (r - nptr[g]);
        } else {
            int e = r - NN;
            int s = eidx[e], d = eidx[NE + e];
            int g = batch[s];
            info_src[tid] = e; info_pu[tid] = s; info_pv[tid] = d;
            info_orow[tid] = g * SEQ + 1 + NPG + (e - eptr[g]);
        }
    }
    __syncthreads();

    const int lane = tid & 63;
    const int wid  = tid >> 6;
    const int lrow = lane & 15;
    const int lq   = lane >> 4;
    const int arow = wid * 16 + lrow;

    // ---- A fragments: gather + convert directly into registers ----
    const int fsrc = info_src[arow];
    const int pu   = info_pu[arow];
    const int pv   = info_pv[arow];
    bf16x8 afr[10];
    #pragma unroll
    for (int s = 0; s < 10; ++s) {
        const int kg = s * 32 + lq * 8;       // 8-k slice, never straddles segments
        const float* sp;
        if      (s < 4) sp = feat + (size_t)fsrc * DN + kg;
        else if (s < 6) sp = P + (size_t)pu * DP + (kg - DN);
        else if (s < 8) sp = P + (size_t)pv * DP + (kg - DN - DP);
        else            sp = idv + (kg - DN - 2 * DP);
        f32x4 f0 = *reinterpret_cast<const f32x4*>(sp);
        f32x4 f1 = *reinterpret_cast<const f32x4*>(sp + 4);
        s16x8 v;
        v[0]=(short)f2bf(f0[0]); v[1]=(short)f2bf(f0[1]);
        v[2]=(short)f2bf(f0[2]); v[3]=(short)f2bf(f0[3]);
        v[4]=(short)f2bf(f1[0]); v[5]=(short)f2bf(f1[1]);
        v[6]=(short)f2bf(f1[2]); v[7]=(short)f2bf(f1[3]);
        afr[s] = __builtin_bit_cast(bf16x8, v);
    }

    // per-lane output row offsets (M rows this lane's acc covers)
    int obase[4];
    #pragma unroll
    for (int j = 0; j < 4; ++j)
        obase[j] = info_orow[wid * 16 + lq * 4 + j] * HD;

    // ---- B prefetch mapping: 512 16B-units = 128 rows x 4 k-slots ----
    const int nl0 = tid >> 2;                 // rows 0..63
    const int nl1 = nl0 + 64;                 // rows 64..127
    const int kb  = (tid & 3) * 16;           // byte offset within 64B k-row

    s16x8 pre0, pre1;
    {   // prologue: (nt=0, kt=0)
        pre0 = *reinterpret_cast<const s16x8*>(Wb + (size_t)nl0 * KD + kb / 2);
        pre1 = *reinterpret_cast<const s16x8*>(Wb + (size_t)nl1 * KD + kb / 2);
    }

    for (int nt = 0; nt < 6; ++nt) {
        const int n0 = nt * 128;
        f32x4 acc[8];
        #pragma unroll
        for (int i = 0; i < 8; ++i) acc[i] = (f32x4)0.f;

        #pragma unroll
        for (int kt = 0; kt < 10; ++kt) {
            char* bb = b_lds[kt & 1];
            // write staged data (loaded one K-step ago; vmem long since landed)
            *reinterpret_cast<s16x8*>(bb + b_off(nl0, kb)) = pre0;
            *reinterpret_cast<s16x8*>(bb + b_off(nl1, kb)) = pre1;
            // issue next tile's loads (consumed next K-step)
            {
                int t  = nt * 10 + kt;
                int tn = (t < 59) ? t + 1 : 59;
                int ntn = tn / 10, ktn = tn - ntn * 10;
                const u16* q = Wb + (size_t)(ntn * 128) * KD + ktn * 32 + kb / 2;
                pre0 = *reinterpret_cast<const s16x8*>(q + (size_t)nl0 * KD);
                pre1 = *reinterpret_cast<const s16x8*>(q + (size_t)nl1 * KD);
            }
            // make our ds_writes visible, then raw barrier (no vmcnt drain)
            asm volatile("s_waitcnt lgkmcnt(0)" ::: "memory");
            __builtin_amdgcn_sched_barrier(0);
            __builtin_amdgcn_s_barrier();
            #pragma unroll
            for (int ni = 0; ni < 8; ++ni) {
                bf16x8 bf = *reinterpret_cast<const bf16x8*>(
                    bb + b_off(ni * 16 + lrow, lq * 16));
                acc[ni] = __builtin_amdgcn_mfma_f32_16x16x32_bf16(afr[kt], bf, acc[ni], 0, 0, 0);
            }
            // reads of bb complete before our next lgkmcnt(0)+barrier, which
            // precedes any write to this buffer two K-steps later.
        }

        // ---- epilogue: bias + direct f32 scatter stores ----
        #pragma unroll
        for (int ni = 0; ni < 8; ++ni) {
            float bv = bias[n0 + ni * 16 + lrow];
            #pragma unroll
            for (int j = 0; j < 4; ++j)
                out[obase[j] + n0 + ni * 16 + lrow] = acc[ni][j] + bv;
        }
    }
}

extern "C" void kernel_launch(void* const* d_in, const int* in_sizes, int n_in,
                              void* d_out, int out_size, void* d_ws, size_t ws_size,
                              hipStream_t stream) {
    const float* x    = (const float*)d_in[0];
    const float* ea   = (const float*)d_in[1];
    const float* P    = (const float*)d_in[2];
    const float* EV   = (const float*)d_in[3];
    const float* EEv  = (const float*)d_in[4];
    const float* W    = (const float*)d_in[5];
    const float* bias = (const float*)d_in[6];
    const float* gt   = (const float*)d_in[7];
    const int* eidx   = (const int*)d_in[8];
    const int* batch  = (const int*)d_in[9];

    float* out = (float*)d_out;
    u16* Wb  = (u16*)d_ws;
    int* ints = (int*)((char*)d_ws + (size_t)KD * HD * 2);
    int *nptr = ints, *eptr = ints + 32;

    ptr_k<<<1, 64, 0, stream>>>(batch, eidx, nptr, eptr);
    wconv_k<<<(KD * HD + 255) / 256, 256, 0, stream>>>(W, Wb);
    aux_k<<<(int)(((size_t)NG * HD + MASK_ELEMS + 255) / 256), 256, 0, stream>>>(gt, out);
    gemm_scatter<<<dim3((NN + NE) / 64), 256, 0, stream>>>(
        x, ea, P, EV, EEv, bias, eidx, batch, Wb, nptr, eptr, out);
}

// Round 5
// 172.189 us; speedup vs baseline: 7.2921x; 1.0352x over previous
//
#include <hip/hip_runtime.h>
#include <stdint.h>

#define NG   32
#define NPG  512
#define EPG  4096
#define DN   128
#define DP   64
#define NN   (NG*NPG)          // 16384 nodes
#define NE   (NG*EPG)          // 131072 edges
#define KD   320               // in_dim
#define HD   768               // hidden
#define SEQ  (1+NPG+EPG)       // 4609
#define TOK_ELEMS ((size_t)NG*SEQ*HD)
#define MASK_ELEMS ((size_t)NG*SEQ)

typedef unsigned short u16;
typedef __attribute__((ext_vector_type(8))) __bf16 bf16x8;
typedef __attribute__((ext_vector_type(8))) short  s16x8;
typedef __attribute__((ext_vector_type(4))) float  f32x4;

__device__ __forceinline__ u16 f2bf(float f) {
    uint32_t u = __builtin_bit_cast(uint32_t, f);
    u += 0x7fffu + ((u >> 16) & 1u);          // RNE
    return (u16)(u >> 16);
}

// B-tile LDS layout: 128 W-rows x 32 k (bf16), rows pair-packed into 128B
// lines, 16B k-slots XOR-swizzled by row-pair bits -> 16-row column-slice
// ds_read_b128 is 2-way (free, m136). Same formula on write and read side.
__device__ __forceinline__ int b_off(int row, int kb) {
    return ((row >> 1) << 7) + ((row & 1) << 6) + (kb ^ (((row >> 1) & 3) << 4));
}

// ---------------- aux kernels ----------------
// Exclusive prefix pointers via binary search (batch / edge graph ids are
// sorted non-decreasing per the reference's packing semantics).
__global__ void ptr_k(const int* __restrict__ batch, const int* __restrict__ eidx,
                      int* __restrict__ nptr, int* __restrict__ eptr) {
    int t = threadIdx.x;
    if (t < NG) {
        int g = t, lo = 0, hi = NN;
        while (lo < hi) { int mid = (lo + hi) >> 1; if (batch[mid] < g) lo = mid + 1; else hi = mid; }
        nptr[g] = lo;
    } else if (t < 2 * NG) {
        int g = t - NG, lo = 0, hi = NE;
        while (lo < hi) { int mid = (lo + hi) >> 1; if (batch[eidx[mid]] < g) lo = mid + 1; else hi = mid; }
        eptr[g] = lo;
    }
}

__global__ void wconv_k(const float* __restrict__ W, u16* __restrict__ Wb) {
    int i = blockIdx.x * 256 + threadIdx.x;
    if (i < KD * HD) Wb[i] = f2bf(W[i]);       // keep [H][K] row-major layout
}

__global__ void aux_k(const float* __restrict__ gt, float* __restrict__ out) {
    size_t i = (size_t)blockIdx.x * 256 + threadIdx.x;
    if (i < (size_t)NG * HD) {
        int g = (int)(i / HD), c = (int)(i % HD);
        out[(size_t)g * SEQ * HD + c] = gt[c];           // [graph] token row
    } else {
        size_t m = i - (size_t)NG * HD;
        if (m < MASK_ELEMS) out[TOK_ELEMS + m] = 1.0f;   // mask = True -> 1.0f
    }
}

// ---------------- main fused gather-GEMM-scatter ----------------
// block = 256 threads (4 waves), 128 A-rows per block; wave w owns rows
// [w*32, w*32+32) as two 16-row fragments. A lives in registers
// (2 x 10 x bf16x8 per lane). B tiles (128 W-rows x 32 k) double-buffered
// in LDS, reg-prefetched one K-step ahead; one raw s_barrier per K-step;
// each B fragment ds_read feeds TWO MFMAs (row-fragment reuse).
__global__ __launch_bounds__(256, 2)
void gemm_scatter(const float* __restrict__ x,  const float* __restrict__ ea,
                  const float* __restrict__ P,  const float* __restrict__ EV,
                  const float* __restrict__ EEv,const float* __restrict__ bias,
                  const int* __restrict__ eidx, const int* __restrict__ batch,
                  const u16* __restrict__ Wb,   const int* __restrict__ nptr,
                  const int* __restrict__ eptr, float* __restrict__ out)
{
    __shared__ __align__(16) char b_lds[2][8192];
    __shared__ int info_src[128], info_pu[128], info_pv[128], info_orow[128];

    const int tid = threadIdx.x;
    const int r0  = blockIdx.x * 128;
    const bool isNode = (r0 < NN);     // NN % 128 == 0: uniform per block
    const float* feat = isNode ? x  : ea;
    const float* idv  = isNode ? EV : EEv;

    if (tid < 128) {
        int r = r0 + tid;
        if (isNode) {
            int g = batch[r];
            info_src[tid] = r; info_pu[tid] = r; info_pv[tid] = r;
            info_orow[tid] = g * SEQ + 1 + (r - nptr[g]);
        } else {
            int e = r - NN;
            int s = eidx[e], d = eidx[NE + e];
            int g = batch[s];
            info_src[tid] = e; info_pu[tid] = s; info_pv[tid] = d;
            info_orow[tid] = g * SEQ + 1 + NPG + (e - eptr[g]);
        }
    }
    __syncthreads();

    const int lane = tid & 63;
    const int wid  = tid >> 6;
    const int lrow = lane & 15;
    const int lq   = lane >> 4;

    // ---- A fragments: gather + convert directly into registers ----
    bf16x8 afr[2][10];
    int obase[2][4];
    #pragma unroll
    for (int rb = 0; rb < 2; ++rb) {
        const int arow = wid * 32 + rb * 16 + lrow;
        const int fsrc = info_src[arow];
        const int pu   = info_pu[arow];
        const int pv   = info_pv[arow];
        #pragma unroll
        for (int s = 0; s < 10; ++s) {
            const int kg = s * 32 + lq * 8;   // 8-k slice, never straddles segments
            const float* sp;
            if      (s < 4) sp = feat + (size_t)fsrc * DN + kg;
            else if (s < 6) sp = P + (size_t)pu * DP + (kg - DN);
            else if (s < 8) sp = P + (size_t)pv * DP + (kg - DN - DP);
            else            sp = idv + (kg - DN - 2 * DP);
            f32x4 f0 = *reinterpret_cast<const f32x4*>(sp);
            f32x4 f1 = *reinterpret_cast<const f32x4*>(sp + 4);
            s16x8 v;
            v[0]=(short)f2bf(f0[0]); v[1]=(short)f2bf(f0[1]);
            v[2]=(short)f2bf(f0[2]); v[3]=(short)f2bf(f0[3]);
            v[4]=(short)f2bf(f1[0]); v[5]=(short)f2bf(f1[1]);
            v[6]=(short)f2bf(f1[2]); v[7]=(short)f2bf(f1[3]);
            afr[rb][s] = __builtin_bit_cast(bf16x8, v);
        }
        #pragma unroll
        for (int j = 0; j < 4; ++j)
            obase[rb][j] = info_orow[wid * 32 + rb * 16 + lq * 4 + j] * HD;
    }

    // ---- B prefetch mapping: 512 16B-units = 128 rows x 4 k-slots ----
    const int nl0 = tid >> 2;                 // rows 0..63
    const int nl1 = nl0 + 64;                 // rows 64..127
    const int kb  = (tid & 3) * 16;           // byte offset within 64B k-row

    s16x8 pre0, pre1;
    {   // prologue: (nt=0, kt=0)
        pre0 = *reinterpret_cast<const s16x8*>(Wb + (size_t)nl0 * KD + kb / 2);
        pre1 = *reinterpret_cast<const s16x8*>(Wb + (size_t)nl1 * KD + kb / 2);
    }

    for (int nt = 0; nt < 6; ++nt) {
        const int n0 = nt * 128;
        f32x4 acc[2][8];
        #pragma unroll
        for (int rb = 0; rb < 2; ++rb)
            #pragma unroll
            for (int i = 0; i < 8; ++i) acc[rb][i] = (f32x4)0.f;

        #pragma unroll
        for (int kt = 0; kt < 10; ++kt) {
            char* bb = b_lds[kt & 1];
            // write staged data (loaded one K-step ago; vmem long since landed)
            *reinterpret_cast<s16x8*>(bb + b_off(nl0, kb)) = pre0;
            *reinterpret_cast<s16x8*>(bb + b_off(nl1, kb)) = pre1;
            // issue next tile's loads (consumed next K-step)
            {
                int t  = nt * 10 + kt;
                int tn = (t < 59) ? t + 1 : 59;
                int ntn = tn / 10, ktn = tn - ntn * 10;
                const u16* q = Wb + (size_t)(ntn * 128) * KD + ktn * 32 + kb / 2;
                pre0 = *reinterpret_cast<const s16x8*>(q + (size_t)nl0 * KD);
                pre1 = *reinterpret_cast<const s16x8*>(q + (size_t)nl1 * KD);
            }
            // make our ds_writes visible, then raw barrier (no vmcnt drain)
            asm volatile("s_waitcnt lgkmcnt(0)" ::: "memory");
            __builtin_amdgcn_sched_barrier(0);
            __builtin_amdgcn_s_barrier();
            #pragma unroll
            for (int ni = 0; ni < 8; ++ni) {
                bf16x8 bf = *reinterpret_cast<const bf16x8*>(
                    bb + b_off(ni * 16 + lrow, lq * 16));
                acc[0][ni] = __builtin_amdgcn_mfma_f32_16x16x32_bf16(afr[0][kt], bf, acc[0][ni], 0, 0, 0);
                acc[1][ni] = __builtin_amdgcn_mfma_f32_16x16x32_bf16(afr[1][kt], bf, acc[1][ni], 0, 0, 0);
            }
            // reads of bb finish before our next lgkmcnt(0)+barrier, which
            // precedes any write to this buffer two K-steps later.
        }

        // ---- epilogue: bias + direct f32 scatter stores ----
        #pragma unroll
        for (int ni = 0; ni < 8; ++ni) {
            float bv = bias[n0 + ni * 16 + lrow];
            #pragma unroll
            for (int rb = 0; rb < 2; ++rb)
                #pragma unroll
                for (int j = 0; j < 4; ++j)
                    out[obase[rb][j] + n0 + ni * 16 + lrow] = acc[rb][ni][j] + bv;
        }
    }
}

extern "C" void kernel_launch(void* const* d_in, const int* in_sizes, int n_in,
                              void* d_out, int out_size, void* d_ws, size_t ws_size,
                              hipStream_t stream) {
    const float* x    = (const float*)d_in[0];
    const float* ea   = (const float*)d_in[1];
    const float* P    = (const float*)d_in[2];
    const float* EV   = (const float*)d_in[3];
    const float* EEv  = (const float*)d_in[4];
    const float* W    = (const float*)d_in[5];
    const float* bias = (const float*)d_in[6];
    const float* gt   = (const float*)d_in[7];
    const int* eidx   = (const int*)d_in[8];
    const int* batch  = (const int*)d_in[9];

    float* out = (float*)d_out;
    u16* Wb  = (u16*)d_ws;
    int* ints = (int*)((char*)d_ws + (size_t)KD * HD * 2);
    int *nptr = ints, *eptr = ints + 32;

    ptr_k<<<1, 64, 0, stream>>>(batch, eidx, nptr, eptr);
    wconv_k<<<(KD * HD + 255) / 256, 256, 0, stream>>>(W, Wb);
    aux_k<<<(int)(((size_t)NG * HD + MASK_ELEMS + 255) / 256), 256, 0, stream>>>(gt, out);
    gemm_scatter<<<dim3((NN + NE) / 128), 256, 0, stream>>>(
        x, ea, P, EV, EEv, bias, eidx, batch, Wb, nptr, eptr, out);
}